// Round 5
// baseline (115.804 us; speedup 1.0000x reference)
//
#include <hip/hip_runtime.h>
#include <math.h>

// Weights / constants from the reference
#define INSIDE_W   0.5f
#define OUTSIDE_W  2.0f
#define CONTACT_W  0.5f
#define HCP_W      1.0f
#define POSE_W     0.01f
#define HANDPOSE_W 0.01f
#define ANGLE_W    0.1f
#define A1c 0.04f
#define A2c 0.04f
#define B1c 0.07f
#define B2c 0.06f
#define C1c 0.01f
#define C2c 0.01f
#define D1c 0.023f
#define D2c 0.02f

#define FBIG 3.402823e38f

typedef float f32x4 __attribute__((ext_vector_type(4)));

__device__ __forceinline__ float waveReduceSum(float x) {
#pragma unroll
    for (int o = 32; o > 0; o >>= 1) x += __shfl_down(x, o, 64);
    return x;
}
__device__ __forceinline__ float waveReduceMin(float x) {
#pragma unroll
    for (int o = 32; o > 0; o >>= 1) x = fminf(x, __shfl_down(x, o, 64));
    return x;
}

// inside[v] without a scatter array: ds is sorted & duplicate-free.
__device__ __forceinline__ bool is_inside(int v, const int* __restrict__ ds,
                                          const int* __restrict__ ext, int NDS) {
    int lo = 0, hi = NDS - 1;
    while (lo <= hi) {
        int mid = (lo + hi) >> 1;
        int dv = ds[mid];
        if (dv == v) return ext[mid] == 0;
        if (dv < v) lo = mid + 1; else hi = mid - 1;
    }
    return false;
}

// accum slots (floats):
// 0: lout_sum 1: lout_cnt 2: rout_sum 3: rout_cnt
// 4: lin_sum  5: lin_cnt  6: rin_sum  7: rin_cnt
// 8: close_cnt
// 9,10,11: nbar_sum xyz
// 12,13,14: S xyz (S = sum over close verts of normalized vn[idx])
// 15: outside_sum
// 16: contact_sum 17: contact_cnt 18: inside_sum 19: inside_cnt

// Init the 4 shifted mask copies to +FBIG.
__global__ __launch_bounds__(256) void k_init_big4(float* __restrict__ big4, int n)
{
    int t = blockIdx.x * blockDim.x + threadIdx.x;
    if (t < n) big4[t] = FBIG;
}

// Scatter -FBIG at contact columns into all 4 shifted copies.
// Copy p holds big[j+p] at index j, so column c lands at index c-p.
__global__ __launch_bounds__(256) void k_scatter_big4(
    float* __restrict__ big4, const int* __restrict__ ivc, int NC, int NVPAD)
{
    int j = blockIdx.x * blockDim.x + threadIdx.x;
    if (j < NC) {
        int c = ivc[j];
#pragma unroll
        for (int p = 0; p < 4; ++p) {
            if (c >= p) big4[(size_t)p * NVPAD + (c - p)] = -FBIG;
        }
    }
}

// K1: gdi[v] = min over contact columns of geodist[v,:] via full-row
// coalesced stream with masked-min (mask L2-resident). Plain store, no atomics.
__global__ __launch_bounds__(256) void k_gdi_stream(
    const float* __restrict__ geodist, const float* __restrict__ big4,
    float* __restrict__ gdi, int NV, int NVPAD)
{
    int v = blockIdx.x;
    size_t base = (size_t)v * (size_t)NV;
    int s = (int)((4 - (base & 3)) & 3);   // scalar prologue length to 16B-align
    const float* row  = geodist + base;
    const float* bigp = big4 + (size_t)s * (size_t)NVPAD; // shifted copy s
    int t = threadIdx.x;
    float m = FBIG;

    if (t < s) m = fminf(m, fmaxf(row[t], big4[t]));  // copy 0 == unshifted

    int nmain = (NV - s) >> 2;
    for (int q = t; q < nmain; q += 256) {
        f32x4 val = __builtin_nontemporal_load((const f32x4*)(row + s + 4 * q));
        f32x4 bg  = *(const f32x4*)(bigp + 4 * q);
        float m0 = fminf(fmaxf(val[0], bg[0]), fmaxf(val[1], bg[1]));
        float m1 = fminf(fmaxf(val[2], bg[2]), fmaxf(val[3], bg[3]));
        m = fminf(m, fminf(m0, m1));
    }

    int tailstart = s + 4 * nmain;
    int ntail = NV - tailstart;
    if (t < ntail) m = fminf(m, fmaxf(row[tailstart + t], big4[tailstart + t]));

    m = waveReduceMin(m);
    __shared__ float sm[4];
    int lane = t & 63;
    int w = t >> 6;
    if (lane == 0) sm[w] = m;
    __syncthreads();
    if (t == 0)
        gdi[v] = fminf(fminf(sm[0], sm[1]), fminf(sm[2], sm[3]));
}

// K2: face-normal scatter-add; close histogram; hand-contact terms;
// ds contact/inside terms (gdi already computed).
__global__ __launch_bounds__(256) void k_scatter(
    const float* __restrict__ verts, const int* __restrict__ faces,
    float* __restrict__ vn,
    const float* __restrict__ v2v_min, const int* __restrict__ v2v_min_idx,
    float* __restrict__ mf, const float* __restrict__ gdi,
    const int* __restrict__ ds, const int* __restrict__ exterior,
    const int* __restrict__ hcp, const float* __restrict__ hcpw,
    float* __restrict__ accum,
    int NF, int NV, int NDS, int HA)
{
    int t = blockIdx.x * blockDim.x + threadIdx.x;
    // face normals
    if (t < NF) {
        int i0 = faces[t * 3 + 0];
        int i1 = faces[t * 3 + 1];
        int i2 = faces[t * 3 + 2];
        float p0x = verts[i0 * 3 + 0], p0y = verts[i0 * 3 + 1], p0z = verts[i0 * 3 + 2];
        float ax = verts[i1 * 3 + 0] - p0x;
        float ay = verts[i1 * 3 + 1] - p0y;
        float az = verts[i1 * 3 + 2] - p0z;
        float bx = verts[i2 * 3 + 0] - p0x;
        float by = verts[i2 * 3 + 1] - p0y;
        float bz = verts[i2 * 3 + 2] - p0z;
        float nx = ay * bz - az * by;
        float ny = az * bx - ax * bz;
        float nz = ax * by - ay * bx;
        atomicAdd(&vn[i0 * 3 + 0], nx);
        atomicAdd(&vn[i0 * 3 + 1], ny);
        atomicAdd(&vn[i0 * 3 + 2], nz);
        atomicAdd(&vn[i1 * 3 + 0], nx);
        atomicAdd(&vn[i1 * 3 + 1], ny);
        atomicAdd(&vn[i1 * 3 + 2], nz);
        atomicAdd(&vn[i2 * 3 + 0], nx);
        atomicAdd(&vn[i2 * 3 + 1], ny);
        atomicAdd(&vn[i2 * 3 + 2], nz);
    }
    float a[13];
#pragma unroll
    for (int k = 0; k < 13; ++k) a[k] = 0.f;
    // close histogram
    if (t < NV) {
        if (v2v_min[t] < 0.01f) {
            atomicAdd(&mf[v2v_min_idx[t]], 1.0f);
            a[8] += 1.0f;  // close_cnt
        }
    }
    // hand contact terms
    if (t < HA) {
        int li = hcp[t];
        int ri = hcp[HA + t];
        float lw = 1.0f - 0.1f * hcpw[t];
        float rw = 1.0f - 0.1f * hcpw[HA + t];
        float lvm = v2v_min[li];
        float rvm = v2v_min[ri];
        if (is_inside(li, ds, exterior, NDS)) {
            a[4] += D1c * tanhf(lvm / D2c);      // lin_sum
            a[5] += 1.0f;
        } else {
            a[0] += lw * C1c * tanhf(lvm / C2c); // lout_sum
            a[1] += 1.0f;
        }
        if (is_inside(ri, ds, exterior, NDS)) {
            a[6] += D1c * tanhf(rvm / D2c);      // rin_sum
            a[7] += 1.0f;
        } else {
            a[2] += rw * C1c * tanhf(rvm / C2c); // rout_sum
            a[3] += 1.0f;
        }
    }
    // ds contact/inside terms
    if (t < NDS) {
        int d = ds[t];
        float vm = v2v_min[d];
        if (exterior[t]) {
            float wo = 1.0f / (5.0f * gdi[d] + 1.0f);
            a[9]  += A1c * wo * tanhf(vm / A2c); // contact_sum
            a[10] += 1.0f;
        } else {
            a[11] += B1c * tanhf(vm / B2c);      // inside_sum
            a[12] += 1.0f;
        }
    }
#pragma unroll
    for (int k = 0; k < 13; ++k) a[k] = waveReduceSum(a[k]);
    __shared__ float s[4][13];
    int lane = threadIdx.x & 63;
    int w = threadIdx.x >> 6;
    if (lane == 0) {
#pragma unroll
        for (int k = 0; k < 13; ++k) s[w][k] = a[k];
    }
    __syncthreads();
    if (threadIdx.x < 13) {
        float v = s[0][threadIdx.x] + s[1][threadIdx.x] + s[2][threadIdx.x] + s[3][threadIdx.x];
        int slot = (threadIdx.x < 9) ? threadIdx.x : (16 + threadIdx.x - 9);
        if (v != 0.f) atomicAdd(&accum[slot], v);
    }
}

// K3: normalize vn in place; reduce nbar_sum, S, and outside_sum.
__global__ __launch_bounds__(256) void k_normalize(
    float* __restrict__ vn, const float* __restrict__ mf,
    const float* __restrict__ gdi,
    const float* __restrict__ verts, const float* __restrict__ iverts,
    float* __restrict__ accum, int NV)
{
    int t = blockIdx.x * blockDim.x + threadIdx.x;
    float a[7] = {0.f, 0.f, 0.f, 0.f, 0.f, 0.f, 0.f};
    if (t < NV) {
        float x = vn[t * 3 + 0];
        float y = vn[t * 3 + 1];
        float z = vn[t * 3 + 2];
        float inv = 1.0f / (sqrtf(x * x + y * y + z * z) + 1e-12f);
        x *= inv; y *= inv; z *= inv;
        vn[t * 3 + 0] = x;
        vn[t * 3 + 1] = y;
        vn[t * 3 + 2] = z;
        a[0] = x; a[1] = y; a[2] = z;
        float mm = mf[t];
        a[3] = mm * x; a[4] = mm * y; a[5] = mm * z;
        float g = gdi[t];
        float dx = iverts[t * 3 + 0] - verts[t * 3 + 0];
        float dy = iverts[t * 3 + 1] - verts[t * 3 + 1];
        float dz = iverts[t * 3 + 2] - verts[t * 3 + 2];
        float v2v0 = sqrtf(dx * dx + dy * dy + dz * dz);
        a[6] = v2v0 * 4.0f * g * g;  // outside_sum
    }
#pragma unroll
    for (int k = 0; k < 7; ++k) a[k] = waveReduceSum(a[k]);
    __shared__ float s[4][7];
    int lane = threadIdx.x & 63;
    int w = threadIdx.x >> 6;
    if (lane == 0) {
#pragma unroll
        for (int k = 0; k < 7; ++k) s[w][k] = a[k];
    }
    __syncthreads();
    if (threadIdx.x < 7) {
        float v = s[0][threadIdx.x] + s[1][threadIdx.x] + s[2][threadIdx.x] + s[3][threadIdx.x];
        if (v != 0.f) atomicAdd(&accum[9 + threadIdx.x], v);
    }
}

// K4: pose sums + final combine (tiny).
__global__ __launch_bounds__(128) void k_final(
    const float* __restrict__ accum,
    const float* __restrict__ bp, const float* __restrict__ ip,
    const float* __restrict__ lh, const float* __restrict__ rh,
    float* __restrict__ out, int NV)
{
    int t = threadIdx.x;
    float pose = 0.f, hand = 0.f;
    if (t < 63) {
        float d = bp[t] - ip[t];
        pose = d * d;
    }
    if (t < 45) {
        hand = lh[t] * lh[t] + rh[t] * rh[t];
    }
    pose = waveReduceSum(pose);
    hand = waveReduceSum(hand);
    __shared__ float s[2][2];
    int lane = t & 63;
    int w = t >> 6;
    if (lane == 0) { s[w][0] = pose; s[w][1] = hand; }
    __syncthreads();
    if (t == 0) {
        pose = s[0][0] + s[1][0];
        hand = s[0][1] + s[1][1];
        float lout_s = accum[0], lout_c = accum[1];
        float rout_s = accum[2], rout_c = accum[3];
        float lin_s  = accum[4], lin_c  = accum[5];
        float rin_s  = accum[6], rin_c  = accum[7];
        float close_c = accum[8];
        float nbx = accum[9]  / (float)NV;
        float nby = accum[10] / (float)NV;
        float nbz = accum[11] / (float)NV;
        float Sdot = accum[12] * nbx + accum[13] * nby + accum[14] * nbz;
        float outside_s = accum[15];
        float contact_s = accum[16], contact_c = accum[17];
        float inside_s  = accum[18], inside_c  = accum[19];

        float contactloss = CONTACT_W * (contact_c > 0.f ? contact_s / contact_c : 0.f);
        float insideloss  = INSIDE_W  * (inside_c  > 0.f ? inside_s  / inside_c  : 0.f);
        float hc_out = (lout_c > 0.f ? lout_s / lout_c : 0.f) + (rout_c > 0.f ? rout_s / rout_c : 0.f);
        float hc_in  = (lin_c  > 0.f ? lin_s  / lin_c  : 0.f) + (rin_c  > 0.f ? rin_s  / rin_c  : 0.f);
        float hand_contact_loss = HCP_W * (hc_in + hc_out);
        float angle_loss = ANGLE_W * (close_c > 0.f ? (close_c + Sdot) / close_c : 0.f);
        float outsideloss = OUTSIDE_W * outside_s;
        float pose_prior_loss = POSE_W * pose;
        float hand_pose_prior_loss = HANDPOSE_W * hand;
        out[0] = contactloss + insideloss + outsideloss + pose_prior_loss +
                 hand_pose_prior_loss + angle_loss + hand_contact_loss;
    }
}

extern "C" void kernel_launch(void* const* d_in, const int* in_sizes, int n_in,
                              void* d_out, int out_size, void* d_ws, size_t ws_size,
                              hipStream_t stream)
{
    const float* verts    = (const float*)d_in[0];
    const float* v2v_min  = (const float*)d_in[1];
    const float* geodist  = (const float*)d_in[2];
    const float* hcpw     = (const float*)d_in[3];
    const float* bp       = (const float*)d_in[4];
    const float* ip       = (const float*)d_in[5];
    const float* lh       = (const float*)d_in[6];
    const float* rh       = (const float*)d_in[7];
    const float* iverts   = (const float*)d_in[8];
    const int*   vmi      = (const int*)d_in[9];
    const int*   exterior = (const int*)d_in[10];
    const int*   ds       = (const int*)d_in[11];
    const int*   ivc      = (const int*)d_in[12];
    const int*   hcp      = (const int*)d_in[13];
    const int*   faces    = (const int*)d_in[14];

    int NV  = in_sizes[1];
    int NDS = in_sizes[11];
    int NC  = in_sizes[12];
    int HA  = in_sizes[13] / 2;
    int NF  = in_sizes[14] / 3;

    int NVPAD = (NV + 15) & ~15;   // keeps each shift-copy 16B aligned

    float* accum = (float*)d_ws;                  // 32 floats
    float* vn    = accum + 32;                    // 3*NV floats
    float* mf    = vn + 3 * (size_t)NV;           // NV floats
    float* gdi   = mf + NV;                       // NV floats (plain-stored)
    size_t off = 32 + 5 * (size_t)NV;
    off = (off + 3) & ~(size_t)3;                 // 16B-align big4
    float* big4  = (float*)d_ws + off;            // 4 * NVPAD floats

    size_t zbytes = (size_t)(32 + 4 * (size_t)NV) * sizeof(float); // accum+vn+mf
    hipMemsetAsync(d_ws, 0, zbytes, stream);

    int nbig = 4 * NVPAD;
    k_init_big4<<<(nbig + 255) / 256, 256, 0, stream>>>(big4, nbig);
    k_scatter_big4<<<(NC + 255) / 256, 256, 0, stream>>>(big4, ivc, NC, NVPAD);

    k_gdi_stream<<<NV, 256, 0, stream>>>(geodist, big4, gdi, NV, NVPAD);

    int nmax = NF > NV ? NF : NV;
    k_scatter<<<(nmax + 255) / 256, 256, 0, stream>>>(
        verts, faces, vn, v2v_min, vmi, mf, gdi, ds, exterior, hcp, hcpw, accum,
        NF, NV, NDS, HA);

    k_normalize<<<(NV + 255) / 256, 256, 0, stream>>>(vn, mf, gdi, verts, iverts, accum, NV);

    k_final<<<1, 128, 0, stream>>>(accum, bp, ip, lh, rh, (float*)d_out, NV);
}

// Round 6
// 100.735 us; speedup vs baseline: 1.1496x; 1.1496x over previous
//
#include <hip/hip_runtime.h>
#include <math.h>

// Weights / constants from the reference
#define INSIDE_W   0.5f
#define OUTSIDE_W  2.0f
#define CONTACT_W  0.5f
#define HCP_W      1.0f
#define POSE_W     0.01f
#define HANDPOSE_W 0.01f
#define ANGLE_W    0.1f
#define A1c 0.04f
#define A2c 0.04f
#define B1c 0.07f
#define B2c 0.06f
#define C1c 0.01f
#define C2c 0.01f
#define D1c 0.023f
#define D2c 0.02f

#define FBIG 3.402823e38f

__device__ __forceinline__ float waveReduceSum(float x) {
#pragma unroll
    for (int o = 32; o > 0; o >>= 1) x += __shfl_down(x, o, 64);
    return x;
}
__device__ __forceinline__ float waveReduceMin(float x) {
#pragma unroll
    for (int o = 32; o > 0; o >>= 1) x = fminf(x, __shfl_down(x, o, 64));
    return x;
}

// inside[v] without a scatter array: ds is sorted & duplicate-free.
__device__ __forceinline__ bool is_inside(int v, const int* __restrict__ ds,
                                          const int* __restrict__ ext, int NDS) {
    int lo = 0, hi = NDS - 1;
    while (lo <= hi) {
        int mid = (lo + hi) >> 1;
        int dv = ds[mid];
        if (dv == v) return ext[mid] == 0;
        if (dv < v) lo = mid + 1; else hi = mid - 1;
    }
    return false;
}

// accum slots (floats):
// 0: lout_sum 1: lout_cnt 2: rout_sum 3: rout_cnt
// 4: lin_sum  5: lin_cnt  6: rin_sum  7: rin_cnt
// 8: close_cnt
// 9,10,11: nbar_sum xyz
// 12,13,14: S xyz (S = sum over close verts of normalized vn[idx])
// 15: outside_sum
// 16: contact_sum 17: contact_cnt 18: inside_sum 19: inside_cnt

// K0: sort the contact-column list ascending (order irrelevant for min;
// ascending gather order improves DRAM row-buffer locality).
__global__ __launch_bounds__(512) void k_sort(
    const int* __restrict__ ivc, int* __restrict__ out, int NC)
{
    __shared__ int sk[512];
    int t = threadIdx.x;
    if (NC <= 512) {
        sk[t] = (t < NC) ? ivc[t] : 0x7FFFFFFF;
        __syncthreads();
        for (int k = 2; k <= 512; k <<= 1) {
            for (int j = k >> 1; j > 0; j >>= 1) {
                int ixj = t ^ j;
                if (ixj > t) {
                    int a = sk[t];
                    int b = sk[ixj];
                    bool up = ((t & k) == 0);
                    if (up ? (a > b) : (a < b)) { sk[t] = b; sk[ixj] = a; }
                }
                __syncthreads();
            }
        }
        if (t < NC) out[t] = sk[t];
    } else {
        for (int j = t; j < NC; j += 512) out[j] = ivc[j];  // fallback: unsorted
    }
}

// K1: gdi[v] = min_j geodist[v, ivcs[j]] (sorted gather, plain store,
// zero atomics). Also zeroes the vn/mf/accum/counter scratch in parallel.
__global__ __launch_bounds__(256) void k_gdi(
    const float* __restrict__ geodist, const int* __restrict__ ivcs,
    float* __restrict__ gdi, float* __restrict__ vn, float* __restrict__ mf,
    float* __restrict__ accum, int* __restrict__ counter, int NV, int NC)
{
    __shared__ int sivc[512];
    int v = blockIdx.x;
    int t = threadIdx.x;
    // scratch zeroing (replaces hipMemsetAsync): disjoint per block
    if (t < 3)  vn[3 * v + t] = 0.f;
    if (t == 3) mf[v] = 0.f;
    if (v == 0) {
        if (t >= 4 && t < 36) accum[t - 4] = 0.f;
        if (t == 36) *counter = 0;
    }
    const float* row = geodist + (size_t)v * (size_t)NV;
    for (int j = t; j < NC && j < 512; j += 256) sivc[j] = ivcs[j];
    __syncthreads();
    float m = FBIG;
    for (int j = t; j < NC; j += 256) {
        int c = (j < 512) ? sivc[j] : ivcs[j];
        m = fminf(m, row[c]);
    }
    m = waveReduceMin(m);
    __shared__ float sm[4];
    int lane = t & 63;
    int w = t >> 6;
    if (lane == 0) sm[w] = m;
    __syncthreads();
    if (t == 0)
        gdi[v] = fminf(fminf(sm[0], sm[1]), fminf(sm[2], sm[3]));
}

// K2: face-normal scatter-add; close histogram; hand-contact terms;
// ds contact/inside terms (gdi already computed).
__global__ __launch_bounds__(256) void k_scatter(
    const float* __restrict__ verts, const int* __restrict__ faces,
    float* __restrict__ vn,
    const float* __restrict__ v2v_min, const int* __restrict__ v2v_min_idx,
    float* __restrict__ mf, const float* __restrict__ gdi,
    const int* __restrict__ ds, const int* __restrict__ exterior,
    const int* __restrict__ hcp, const float* __restrict__ hcpw,
    float* __restrict__ accum,
    int NF, int NV, int NDS, int HA)
{
    int t = blockIdx.x * blockDim.x + threadIdx.x;
    // face normals
    if (t < NF) {
        int i0 = faces[t * 3 + 0];
        int i1 = faces[t * 3 + 1];
        int i2 = faces[t * 3 + 2];
        float p0x = verts[i0 * 3 + 0], p0y = verts[i0 * 3 + 1], p0z = verts[i0 * 3 + 2];
        float ax = verts[i1 * 3 + 0] - p0x;
        float ay = verts[i1 * 3 + 1] - p0y;
        float az = verts[i1 * 3 + 2] - p0z;
        float bx = verts[i2 * 3 + 0] - p0x;
        float by = verts[i2 * 3 + 1] - p0y;
        float bz = verts[i2 * 3 + 2] - p0z;
        float nx = ay * bz - az * by;
        float ny = az * bx - ax * bz;
        float nz = ax * by - ay * bx;
        atomicAdd(&vn[i0 * 3 + 0], nx);
        atomicAdd(&vn[i0 * 3 + 1], ny);
        atomicAdd(&vn[i0 * 3 + 2], nz);
        atomicAdd(&vn[i1 * 3 + 0], nx);
        atomicAdd(&vn[i1 * 3 + 1], ny);
        atomicAdd(&vn[i1 * 3 + 2], nz);
        atomicAdd(&vn[i2 * 3 + 0], nx);
        atomicAdd(&vn[i2 * 3 + 1], ny);
        atomicAdd(&vn[i2 * 3 + 2], nz);
    }
    float a[13];
#pragma unroll
    for (int k = 0; k < 13; ++k) a[k] = 0.f;
    // close histogram
    if (t < NV) {
        if (v2v_min[t] < 0.01f) {
            atomicAdd(&mf[v2v_min_idx[t]], 1.0f);
            a[8] += 1.0f;  // close_cnt
        }
    }
    // hand contact terms
    if (t < HA) {
        int li = hcp[t];
        int ri = hcp[HA + t];
        float lw = 1.0f - 0.1f * hcpw[t];
        float rw = 1.0f - 0.1f * hcpw[HA + t];
        float lvm = v2v_min[li];
        float rvm = v2v_min[ri];
        if (is_inside(li, ds, exterior, NDS)) {
            a[4] += D1c * tanhf(lvm / D2c);      // lin_sum
            a[5] += 1.0f;
        } else {
            a[0] += lw * C1c * tanhf(lvm / C2c); // lout_sum
            a[1] += 1.0f;
        }
        if (is_inside(ri, ds, exterior, NDS)) {
            a[6] += D1c * tanhf(rvm / D2c);      // rin_sum
            a[7] += 1.0f;
        } else {
            a[2] += rw * C1c * tanhf(rvm / C2c); // rout_sum
            a[3] += 1.0f;
        }
    }
    // ds contact/inside terms
    if (t < NDS) {
        int d = ds[t];
        float vm = v2v_min[d];
        if (exterior[t]) {
            float wo = 1.0f / (5.0f * gdi[d] + 1.0f);
            a[9]  += A1c * wo * tanhf(vm / A2c); // contact_sum
            a[10] += 1.0f;
        } else {
            a[11] += B1c * tanhf(vm / B2c);      // inside_sum
            a[12] += 1.0f;
        }
    }
#pragma unroll
    for (int k = 0; k < 13; ++k) a[k] = waveReduceSum(a[k]);
    __shared__ float s[4][13];
    int lane = threadIdx.x & 63;
    int w = threadIdx.x >> 6;
    if (lane == 0) {
#pragma unroll
        for (int k = 0; k < 13; ++k) s[w][k] = a[k];
    }
    __syncthreads();
    if (threadIdx.x < 13) {
        float v = s[0][threadIdx.x] + s[1][threadIdx.x] + s[2][threadIdx.x] + s[3][threadIdx.x];
        int slot = (threadIdx.x < 9) ? threadIdx.x : (16 + threadIdx.x - 9);
        if (v != 0.f) atomicAdd(&accum[slot], v);
    }
}

// K3: normalize vn; reduce nbar_sum, S, outside_sum; LAST block to finish
// (atomic ticket) computes pose sums and the final combine.
__global__ __launch_bounds__(256) void k_normalize(
    float* __restrict__ vn, const float* __restrict__ mf,
    const float* __restrict__ gdi,
    const float* __restrict__ verts, const float* __restrict__ iverts,
    float* __restrict__ accum, int* __restrict__ counter,
    const float* __restrict__ bp, const float* __restrict__ ip,
    const float* __restrict__ lh, const float* __restrict__ rh,
    float* __restrict__ out, int NV)
{
    int tid = threadIdx.x;
    int t = blockIdx.x * blockDim.x + tid;
    float a[7] = {0.f, 0.f, 0.f, 0.f, 0.f, 0.f, 0.f};
    if (t < NV) {
        float x = vn[t * 3 + 0];
        float y = vn[t * 3 + 1];
        float z = vn[t * 3 + 2];
        float inv = 1.0f / (sqrtf(x * x + y * y + z * z) + 1e-12f);
        x *= inv; y *= inv; z *= inv;
        a[0] = x; a[1] = y; a[2] = z;
        float mm = mf[t];
        a[3] = mm * x; a[4] = mm * y; a[5] = mm * z;
        float g = gdi[t];
        float dx = iverts[t * 3 + 0] - verts[t * 3 + 0];
        float dy = iverts[t * 3 + 1] - verts[t * 3 + 1];
        float dz = iverts[t * 3 + 2] - verts[t * 3 + 2];
        float v2v0 = sqrtf(dx * dx + dy * dy + dz * dz);
        a[6] = v2v0 * 4.0f * g * g;  // outside_sum
    }
#pragma unroll
    for (int k = 0; k < 7; ++k) a[k] = waveReduceSum(a[k]);
    __shared__ float s[4][7];
    int lane = tid & 63;
    int w = tid >> 6;
    if (lane == 0) {
#pragma unroll
        for (int k = 0; k < 7; ++k) s[w][k] = a[k];
    }
    __syncthreads();
    if (tid < 7) {
        float v = s[0][tid] + s[1][tid] + s[2][tid] + s[3][tid];
        if (v != 0.f) atomicAdd(&accum[9 + tid], v);
    }
    // --- last-block-finishes final combine ---
    __shared__ int sticket;
    __syncthreads();
    if (tid == 0) {
        __threadfence();
        sticket = atomicAdd(counter, 1);
    }
    __syncthreads();
    if (sticket == (int)gridDim.x - 1) {
        __threadfence();
        float pose = 0.f, hand = 0.f;
        if (tid < 63) {
            float d = bp[tid] - ip[tid];
            pose = d * d;
        }
        if (tid < 45) {
            hand = lh[tid] * lh[tid] + rh[tid] * rh[tid];
        }
        pose = waveReduceSum(pose);
        hand = waveReduceSum(hand);
        __shared__ float sp[4][2];
        if (lane == 0) { sp[w][0] = pose; sp[w][1] = hand; }
        __syncthreads();
        if (tid == 0) {
            pose = sp[0][0] + sp[1][0] + sp[2][0] + sp[3][0];
            hand = sp[0][1] + sp[1][1] + sp[2][1] + sp[3][1];
            float ac[20];
#pragma unroll
            for (int k = 0; k < 20; ++k)
                ac[k] = __hip_atomic_load(&accum[k], __ATOMIC_RELAXED,
                                          __HIP_MEMORY_SCOPE_AGENT);
            float lout_s = ac[0], lout_c = ac[1];
            float rout_s = ac[2], rout_c = ac[3];
            float lin_s  = ac[4], lin_c  = ac[5];
            float rin_s  = ac[6], rin_c  = ac[7];
            float close_c = ac[8];
            float nbx = ac[9]  / (float)NV;
            float nby = ac[10] / (float)NV;
            float nbz = ac[11] / (float)NV;
            float Sdot = ac[12] * nbx + ac[13] * nby + ac[14] * nbz;
            float outside_s = ac[15];
            float contact_s = ac[16], contact_c = ac[17];
            float inside_s  = ac[18], inside_c  = ac[19];

            float contactloss = CONTACT_W * (contact_c > 0.f ? contact_s / contact_c : 0.f);
            float insideloss  = INSIDE_W  * (inside_c  > 0.f ? inside_s  / inside_c  : 0.f);
            float hc_out = (lout_c > 0.f ? lout_s / lout_c : 0.f) + (rout_c > 0.f ? rout_s / rout_c : 0.f);
            float hc_in  = (lin_c  > 0.f ? lin_s  / lin_c  : 0.f) + (rin_c  > 0.f ? rin_s  / rin_c  : 0.f);
            float hand_contact_loss = HCP_W * (hc_in + hc_out);
            float angle_loss = ANGLE_W * (close_c > 0.f ? (close_c + Sdot) / close_c : 0.f);
            float outsideloss = OUTSIDE_W * outside_s;
            float pose_prior_loss = POSE_W * pose;
            float hand_pose_prior_loss = HANDPOSE_W * hand;
            out[0] = contactloss + insideloss + outsideloss + pose_prior_loss +
                     hand_pose_prior_loss + angle_loss + hand_contact_loss;
        }
    }
}

extern "C" void kernel_launch(void* const* d_in, const int* in_sizes, int n_in,
                              void* d_out, int out_size, void* d_ws, size_t ws_size,
                              hipStream_t stream)
{
    const float* verts    = (const float*)d_in[0];
    const float* v2v_min  = (const float*)d_in[1];
    const float* geodist  = (const float*)d_in[2];
    const float* hcpw     = (const float*)d_in[3];
    const float* bp       = (const float*)d_in[4];
    const float* ip       = (const float*)d_in[5];
    const float* lh       = (const float*)d_in[6];
    const float* rh       = (const float*)d_in[7];
    const float* iverts   = (const float*)d_in[8];
    const int*   vmi      = (const int*)d_in[9];
    const int*   exterior = (const int*)d_in[10];
    const int*   ds       = (const int*)d_in[11];
    const int*   ivc      = (const int*)d_in[12];
    const int*   hcp      = (const int*)d_in[13];
    const int*   faces    = (const int*)d_in[14];

    int NV  = in_sizes[1];
    int NDS = in_sizes[11];
    int NC  = in_sizes[12];
    int HA  = in_sizes[13] / 2;
    int NF  = in_sizes[14] / 3;

    float* accum = (float*)d_ws;                  // 32 floats (zeroed in k_gdi)
    float* vn    = accum + 32;                    // 3*NV floats (zeroed in k_gdi)
    float* mf    = vn + 3 * (size_t)NV;           // NV floats (zeroed in k_gdi)
    float* gdi   = mf + NV;                       // NV floats (plain-stored)
    int*   ivcs  = (int*)(gdi + NV);              // NC ints (sorted columns)
    int*   counter = ivcs + NC;                   // 1 int (zeroed in k_gdi)

    // K0: sort contact columns ascending (order-invariant for min)
    k_sort<<<1, 512, 0, stream>>>(ivc, ivcs, NC);

    // K1: sorted gather min + scratch zeroing
    k_gdi<<<NV, 256, 0, stream>>>(geodist, ivcs, gdi, vn, mf, accum, counter, NV, NC);

    int nmax = NF > NV ? NF : NV;
    k_scatter<<<(nmax + 255) / 256, 256, 0, stream>>>(
        verts, faces, vn, v2v_min, vmi, mf, gdi, ds, exterior, hcp, hcpw, accum,
        NF, NV, NDS, HA);

    int nblk = (NV + 255) / 256;
    k_normalize<<<nblk, 256, 0, stream>>>(vn, mf, gdi, verts, iverts, accum, counter,
                                          bp, ip, lh, rh, (float*)d_out, NV);
}